// Round 1
// baseline (1025.595 us; speedup 1.0000x reference)
//
#include <hip/hip_runtime.h>
#include <math.h>

#define TWO_PI 6.28318530717958647692f

// Problem: B=16, C=64, H=W=256, M1=M2=32.
// Kept modes: k1 in {0..31} (w1) and {224..255} (w2)  -> s index 0..63, f = s<32 ? s : s+192
//             k2 in {0..31}
// out = irfft2 of the projected spectrum. Only Re survives; Im of k2==0 column drops.

// ---------------------------------------------------------------------------
// Kernel 1: wsum[c,m1,m2] = (1/65536) * sum_j (w_real + i w_imag)[j,c,m1,m2]
// (irfft2 1/(H*W) normalization folded in here)
// ---------------------------------------------------------------------------
__global__ __launch_bounds__(256)
void wsum_kernel(const float* __restrict__ w1r, const float* __restrict__ w1i,
                 const float* __restrict__ w2r, const float* __restrict__ w2i,
                 float2* __restrict__ s1, float2* __restrict__ s2) {
    int e = blockIdx.x * 256 + threadIdx.x;   // [0, 65536) = c*1024 + m1*32 + m2
    float a = 0.f, b = 0.f, c = 0.f, d = 0.f;
    #pragma unroll 4
    for (int j = 0; j < 64; ++j) {
        int idx = j * 65536 + e;
        a += w1r[idx]; b += w1i[idx];
        c += w2r[idx]; d += w2i[idx];
    }
    const float sc = 1.0f / 65536.0f;
    s1[e] = make_float2(a * sc, b * sc);
    s2[e] = make_float2(c * sc, d * sc);
}

// ---------------------------------------------------------------------------
// Kernel 2 (forward): per (b,c) image, X[s,k2] = sum_h sum_w x[h,w] e^{-2pi i (f h + k2 w)/256}
// Block = 256 threads = one image. Row-DFT via 8 partial sums of 32 w each
// (complex-rotation recurrence), then per-thread register accumulation over h.
// ---------------------------------------------------------------------------
__global__ __launch_bounds__(256)
void fwd_kernel(const float* __restrict__ x, float2* __restrict__ X) {
    const int bc = blockIdx.x;        // b*64 + c
    const int t  = threadIdx.x;

    __shared__ float cs[256], sn[256];
    __shared__ float xrow[256];
    __shared__ float pw_re[8][32];
    __shared__ float pw_im[8][32];
    __shared__ float Xw_re[32], Xw_im[32];

    {   // twiddle table: cs/sn[n] = cos/sin(2 pi n / 256)
        float ang = (TWO_PI / 256.0f) * (float)t;
        float s_, c_;
        sincosf(ang, &s_, &c_);
        cs[t] = c_; sn[t] = s_;
    }

    // row-DFT thread constants: thread covers k2 = t&31, w in [32*prt, 32*prt+32)
    const int k2  = t & 31;
    const int prt = t >> 5;
    float c0, s0, rc, rs;
    {
        int n0 = (k2 * prt * 32) & 255;                 // start phase index
        float a0 = -(TWO_PI / 256.0f) * (float)n0;
        sincosf(a0, &s0, &c0);                          // e^{-2pi i k2*32*prt/256}
        float ar = -(TWO_PI / 256.0f) * (float)k2;
        sincosf(ar, &rs, &rc);                          // per-w rotation e^{-2pi i k2/256}
    }

    // h-accumulation thread constants: thread owns s = t>>2 (fixed), k2 = k2b..k2b+7
    const int sidx = t >> 2;                  // 0..63
    const int k2b  = (t & 3) * 8;
    const int f    = (sidx < 32) ? sidx : (sidx + 192);
    float accR[8], accI[8];
    #pragma unroll
    for (int i = 0; i < 8; ++i) { accR[i] = 0.f; accI[i] = 0.f; }

    const float* xim = x + (size_t)bc * 65536;
    __syncthreads();

    for (int h = 0; h < 256; ++h) {
        xrow[t] = xim[h * 256 + t];
        __syncthreads();
        // partial row DFT
        float cr = c0, ci = s0;
        float ar = 0.f, ai = 0.f;
        const int wb = prt * 32;
        #pragma unroll
        for (int i = 0; i < 32; ++i) {
            float xv = xrow[wb + i];
            ar = fmaf(xv, cr, ar);
            ai = fmaf(xv, ci, ai);
            float nc = cr * rc - ci * rs;
            float ns = ci * rc + cr * rs;
            cr = nc; ci = ns;
        }
        pw_re[prt][k2] = ar;
        pw_im[prt][k2] = ai;
        __syncthreads();
        if (t < 64) {                         // reduce 8 partials -> Xw
            int kk = t & 31;
            float v = 0.f;
            if (t < 32) {
                #pragma unroll
                for (int p = 0; p < 8; ++p) v += pw_re[p][kk];
                Xw_re[kk] = v;
            } else {
                #pragma unroll
                for (int p = 0; p < 8; ++p) v += pw_im[p][kk];
                Xw_im[kk] = v;
            }
        }
        __syncthreads();
        // X[f,k2] += Xw[k2] * e^{-2pi i f h/256} = Xw * (tc - i ts)
        int n = (f * h) & 255;
        float tc = cs[n], ts = sn[n];
        const float4* wr4 = (const float4*)&Xw_re[k2b];
        const float4* wi4 = (const float4*)&Xw_im[k2b];
        float4 wr0 = wr4[0], wr1 = wr4[1];
        float4 wi0 = wi4[0], wi1 = wi4[1];
        float wr[8] = {wr0.x, wr0.y, wr0.z, wr0.w, wr1.x, wr1.y, wr1.z, wr1.w};
        float wi[8] = {wi0.x, wi0.y, wi0.z, wi0.w, wi1.x, wi1.y, wi1.z, wi1.w};
        #pragma unroll
        for (int i = 0; i < 8; ++i) {
            accR[i] = fmaf(wr[i], tc, fmaf(wi[i],  ts, accR[i]));
            accI[i] = fmaf(wi[i], tc, fmaf(wr[i], -ts, accI[i]));
        }
    }
    // flat layout per image: [s][k2], entry t*8+i == (t>>2)*32 + (t&3)*8 + i
    float2* Xp = X + (size_t)bc * 2048 + t * 8;
    #pragma unroll
    for (int i = 0; i < 8; ++i) Xp[i] = make_float2(accR[i], accI[i]);
}

// ---------------------------------------------------------------------------
// Kernel 3 (inverse): per (b,c) image.
//   G[s,k2] = X[s,k2] * wsum[c, m1(s), k2]          (into LDS)
//   tmp[h,k2] = sum_s G[s,k2] e^{+2pi i f h/256}    (64-h chunks in LDS)
//   out[h,w]  = Re(tmp[h,0]) + 2 * sum_{k2=1..31} Re(tmp[h,k2] e^{+2pi i k2 w/256})
// ---------------------------------------------------------------------------
__global__ __launch_bounds__(256)
void inv_kernel(const float2* __restrict__ X,
                const float2* __restrict__ s1, const float2* __restrict__ s2,
                float* __restrict__ out) {
    const int bc = blockIdx.x;
    const int c  = bc & 63;
    const int t  = threadIdx.x;

    __shared__ float cs[256], sn[256];
    __shared__ float G_re[2048], G_im[2048];
    __shared__ float t_re[2048], t_im[2048];   // 64 h x 32 k2 chunk

    float cw, sw;   // e^{+2pi i w/256}, w = t (also the table entry)
    {
        float ang = (TWO_PI / 256.0f) * (float)t;
        sincosf(ang, &sw, &cw);
        cs[t] = cw; sn[t] = sw;
    }

    const int sidx = t >> 2;
    const int k2b  = (t & 3) * 8;

    {   // G = X * wsum
        const float2* Xp = X + (size_t)bc * 2048 + t * 8;
        const float2* wp = (sidx < 32) ? (s1 + c * 1024 + sidx * 32 + k2b)
                                       : (s2 + c * 1024 + (sidx - 32) * 32 + k2b);
        #pragma unroll
        for (int i = 0; i < 8; ++i) {
            float2 xv = Xp[i];
            float2 wv = wp[i];
            G_re[t * 8 + i] = xv.x * wv.x - xv.y * wv.y;
            G_im[t * 8 + i] = xv.x * wv.y + xv.y * wv.x;
        }
    }
    __syncthreads();

    float* oim = out + (size_t)bc * 65536;

    for (int h0 = 0; h0 < 256; h0 += 64) {
        // tmp stage: thread owns h = h0 + (t>>2), k2 = k2b..k2b+7
        const int h = h0 + (t >> 2);
        float aR[8], aI[8];
        #pragma unroll
        for (int i = 0; i < 8; ++i) { aR[i] = 0.f; aI[i] = 0.f; }
        for (int s = 0; s < 64; ++s) {
            int ff = (s < 32) ? s : (s + 192);
            int n  = (ff * h) & 255;
            float tc = cs[n], ts = sn[n];       // e^{+2pi i ff h/256}
            const float4* gr4 = (const float4*)&G_re[s * 32 + k2b];
            const float4* gi4 = (const float4*)&G_im[s * 32 + k2b];
            float4 g0 = gr4[0], g1 = gr4[1];
            float4 m0 = gi4[0], m1 = gi4[1];
            float gr[8] = {g0.x, g0.y, g0.z, g0.w, g1.x, g1.y, g1.z, g1.w};
            float gi[8] = {m0.x, m0.y, m0.z, m0.w, m1.x, m1.y, m1.z, m1.w};
            #pragma unroll
            for (int i = 0; i < 8; ++i) {
                aR[i] = fmaf(gr[i], tc, fmaf(gi[i], -ts, aR[i]));
                aI[i] = fmaf(gr[i], ts, fmaf(gi[i],  tc, aI[i]));
            }
        }
        const int hl = t >> 2;
        #pragma unroll
        for (int i = 0; i < 8; ++i) {
            t_re[hl * 32 + k2b + i] = aR[i];
            t_im[hl * 32 + k2b + i] = aI[i];
        }
        __syncthreads();
        // out stage: thread = column w = t; rotation recurrence over k2
        for (int r = 0; r < 64; ++r) {
            const float* tr = &t_re[r * 32];
            const float* ti = &t_im[r * 32];
            float acc = 0.f;
            float ccur = cw, scur = sw;         // k2 = 1 twiddle
            #pragma unroll
            for (int k = 1; k < 32; ++k) {
                acc = fmaf(tr[k], ccur, acc);
                acc = fmaf(-ti[k], scur, acc);
                float nc = ccur * cw - scur * sw;
                float ns = scur * cw + ccur * sw;
                ccur = nc; scur = ns;
            }
            oim[(h0 + r) * 256 + t] = fmaf(2.f, acc, tr[0]);
        }
        __syncthreads();
    }
}

// ---------------------------------------------------------------------------
extern "C" void kernel_launch(void* const* d_in, const int* in_sizes, int n_in,
                              void* d_out, int out_size, void* d_ws, size_t ws_size,
                              hipStream_t stream) {
    const float* x   = (const float*)d_in[0];
    const float* w1r = (const float*)d_in[1];
    const float* w1i = (const float*)d_in[2];
    const float* w2r = (const float*)d_in[3];
    const float* w2i = (const float*)d_in[4];
    float* out = (float*)d_out;

    char* ws = (char*)d_ws;
    float2* X  = (float2*)ws;                          // 1024*2048 float2 = 16 MiB
    float2* s1 = (float2*)(ws + 16777216);             // 65536 float2 = 512 KiB
    float2* s2 = (float2*)(ws + 16777216 + 524288);    // 65536 float2 = 512 KiB

    hipLaunchKernelGGL(wsum_kernel, dim3(256), dim3(256), 0, stream,
                       w1r, w1i, w2r, w2i, s1, s2);
    hipLaunchKernelGGL(fwd_kernel, dim3(1024), dim3(256), 0, stream, x, X);
    hipLaunchKernelGGL(inv_kernel, dim3(1024), dim3(256), 0, stream, X, s1, s2, out);
}